// Round 1
// baseline (248.326 us; speedup 1.0000x reference)
//
#include <hip/hip_runtime.h>

// Problem constants (from reference)
#define NV      163842      // vertices
#define CIN     64
#define KN      7
#define NKMAX   (NV * KN)   // 1,146,894 valid neigh entries
#define KDIM    448         // 7*64
#define KSTEPS  14          // 448 / 32
#define VPC     16          // vertices per chunk
#define ROWS    32          // M-rows per chunk (VPC * 2 batches)
#define ASTRIDE 456         // LDS row stride in bf16 units (448 + 8 pad; 912B, 16B-aligned)
#define ABUF    (ROWS * ASTRIDE)   // shorts per A buffer (14592; 29184 B)

typedef short  short8 __attribute__((ext_vector_type(8)));
typedef float  f32x4  __attribute__((ext_vector_type(4)));
typedef float  f32x2  __attribute__((ext_vector_type(2)));

static __device__ __forceinline__ unsigned int pack_bf16(float a, float b) {
#if __has_builtin(__builtin_amdgcn_cvt_pk_bf16_f32)
    typedef __bf16 bf16x2 __attribute__((ext_vector_type(2)));
    union { bf16x2 v; unsigned int u; } cv;
    cv.v = __builtin_amdgcn_cvt_pk_bf16_f32(a, b);
    return cv.u;
#else
    unsigned int ua = __float_as_uint(a);
    unsigned int ub = __float_as_uint(b);
    ua = (ua + 0x7FFFu + ((ua >> 16) & 1u)) >> 16;
    ub = (ub + 0x7FFFu + ((ub >> 16) & 1u)) & 0xFFFF0000u;
    return ua | ub;
#endif
}

// LDS-only barrier: drains lgkmcnt but leaves the vmcnt (global prefetch) queue
// alive across s_barrier. __syncthreads() would emit s_waitcnt vmcnt(0) and
// destroy the cross-chunk pipeline.
static __device__ __forceinline__ void bar_lgkm() {
    asm volatile("s_waitcnt lgkmcnt(0)\n\ts_barrier" ::: "memory");
}

// ---- pre-pass: x [N][C][B] fp32 -> x_t [B][N][C] bf16 (de-interleave + cast) ----
__global__ __launch_bounds__(256)
void xcast(const float* __restrict__ x, unsigned int* __restrict__ xt, int nf4)
{
    const int f = blockIdx.x * 256 + threadIdx.x;   // float4 index over x
    if (f >= nf4) return;                           // nf4 = NV*32
    const f32x4 g = __builtin_nontemporal_load(&((const f32x4*)x)[f]);
    const int v = f >> 5;
    const int r = f & 31;                           // u32 slot; c0 = 2r
    xt[v * 32 + r]           = pack_bf16(g[0], g[2]); // batch 0: c0, c0+1
    xt[NV * 32 + v * 32 + r] = pack_bf16(g[1], g[3]); // batch 1
}

// ---- main v2: 512-thread block, double-buffered A_lds, ONE barrier/chunk,
//      C_lds removed (direct coalesced float2 nt stores from accumulators) ----
__global__ __launch_bounds__(512, 4)
void onering_mfma_bf16_v2(const unsigned short* __restrict__ xt,
                          const int* __restrict__ neigh,
                          const float* __restrict__ W,
                          const float* __restrict__ bias,
                          float* __restrict__ out,
                          int nchunks)
{
    // 2 x 29184 B double buffer = 58368 B (2 blocks/CU -> 16 waves/CU)
    __shared__ __align__(16) unsigned short A_lds[2 * ABUF];

    const int tid  = threadIdx.x;
    const int lane = tid & 63;
    const int wid  = tid >> 6;       // 0..7
    const int wc   = wid & 3;        // col tile (16 out-cols each)
    const int wr   = wid >> 2;       // row tile (rows 0-15 / 16-31)
    const int ncol = lane & 15;
    const int kgrp = lane >> 4;
    const int G    = gridDim.x;

    // ---- persistent B fragments: W (fp32) -> bf16, register-resident (56 VGPR) ----
    short8 bfrag[KSTEPS];
    {
        const int o = wc * 16 + ncol;
#pragma unroll
        for (int s = 0; s < KSTEPS; ++s) {
            const int kb = s * 32 + kgrp * 8;
            const float4* wp = (const float4*)(W + o * KDIM + kb);
            float4 w0 = wp[0];
            float4 w1 = wp[1];
            union { short8 v; unsigned int u[4]; } pk;
            pk.u[0] = pack_bf16(w0.x, w0.y);
            pk.u[1] = pack_bf16(w0.z, w0.w);
            pk.u[2] = pack_bf16(w1.x, w1.y);
            pk.u[3] = pack_bf16(w1.z, w1.w);
            bfrag[s] = pk.v;
        }
    }
    const float biasv = bias[wc * 16 + ncol];

    // ---- staging plan: 224 segments (row 0..31, k 0..6), 8 lanes x 16B each.
    //      512 threads: i=0..2 always active, i==3 only tid<256 (wave-uniform). ----
    const int l8 = tid & 7;
    int nidx[4];      // neigh offset within chunk (lv*7 + k)
    int lbyte[4];     // byte addr within one A buffer
    int soff[4];      // short offset within xt: bb*NV*64 + l8*8
#pragma unroll
    for (int i = 0; i < 4; ++i) {
        const int seg = (tid >> 3) + 64 * i;
        const int row = seg / 7;
        const int k   = seg - row * 7;
        const int lv  = row >> 1, bb = row & 1;
        nidx[i]  = lv * KN + k;
        lbyte[i] = row * (ASTRIDE * 2) + k * 128 + l8 * 16;
        soff[i]  = bb * (NV * 64) + l8 * 8;
    }
    const bool act3 = (tid < 256);   // segs 224..255 are bogus -> skip (uniform per wave)

    const int ch0 = blockIdx.x;
    int    I[4];      // neigh indices (pipeline stage: ch+2G)
    short8 R[4];      // gathered rows   (pipeline stage: ch+G)

    // ---- prologue: fill the 3-stage pipeline; stage ch0 into buffer 0 ----
#pragma unroll
    for (int i = 0; i < 4; ++i)
        if (i < 3 || act3) {
            int gi = ch0 * (VPC * KN) + nidx[i];
            I[i] = __builtin_nontemporal_load(&neigh[gi < NKMAX ? gi : 0]);
        }
#pragma unroll
    for (int i = 0; i < 4; ++i)
        if (i < 3 || act3) R[i] = *(const short8*)(xt + soff[i] + I[i] * 64);
#pragma unroll
    for (int i = 0; i < 4; ++i)
        if (i < 3 || act3) *(short8*)((char*)A_lds + lbyte[i]) = R[i];
#pragma unroll
    for (int i = 0; i < 4; ++i)
        if (i < 3 || act3) {
            int gi = (ch0 + G) * (VPC * KN) + nidx[i];
            I[i] = __builtin_nontemporal_load(&neigh[gi < NKMAX ? gi : 0]);
        }
#pragma unroll
    for (int i = 0; i < 4; ++i)
        if (i < 3 || act3) R[i] = *(const short8*)(xt + soff[i] + I[i] * 64);
#pragma unroll
    for (int i = 0; i < 4; ++i)
        if (i < 3 || act3) {
            int gi = (ch0 + 2 * G) * (VPC * KN) + nidx[i];
            I[i] = __builtin_nontemporal_load(&neigh[gi < NKMAX ? gi : 0]);
        }
    bar_lgkm();   // A[0] = ch0 visible to all waves; R=ch0+G in flight; I=ch0+2G in flight

    int rbuf = 0;
    for (int ch = ch0; ch < nchunks; ch += G) {
        const int vb = ch * VPC;

        // ---- stage chunk ch+G into the BACK buffer (no sync needed vs compute:
        //      different buffer; barrier at loop end publishes it) ----
        char* wbase = (char*)A_lds + (rbuf ^ 1) * (ABUF * 2);
#pragma unroll
        for (int i = 0; i < 4; ++i)
            if (i < 3 || act3) *(short8*)(wbase + lbyte[i]) = R[i];
#pragma unroll
        for (int i = 0; i < 4; ++i)                       // gather ch+2G
            if (i < 3 || act3) R[i] = *(const short8*)(xt + soff[i] + I[i] * 64);
#pragma unroll
        for (int i = 0; i < 4; ++i)                       // idx for ch+3G
            if (i < 3 || act3) {
                int gi = (ch + 3 * G) * (VPC * KN) + nidx[i];
                I[i] = __builtin_nontemporal_load(&neigh[gi < NKMAX ? gi : 0]);
            }

        // ---- compute chunk ch from the FRONT buffer: 1 row-tile x 16 out-cols ----
        const unsigned short* Ap = A_lds + rbuf * ABUF + (wr * 16 + ncol) * ASTRIDE;
        f32x4 acc = {0.f, 0.f, 0.f, 0.f};
#pragma unroll
        for (int s = 0; s < KSTEPS; ++s) {
            const short8 a = *(const short8*)&Ap[s * 32 + kgrp * 8];
            acc = __builtin_amdgcn_mfma_f32_16x16x32_bf16(a, bfrag[s], acc, 0, 0, 0);
        }

        // ---- direct coalesced nt stores: lane pairs (acc[2jp],acc[2jp+1]) =
        //      batches 0/1 of vertex vb + wr*8 + kgrp*2 + jp; 16 lanes x 8 B
        //      = 128 B fully-written segment per kgrp row. ----
        const int ocol = (wc * 16 + ncol) * 2;
        const int v0   = vb + wr * 8 + kgrp * 2;
#pragma unroll
        for (int jp = 0; jp < 2; ++jp) {
            const int n = v0 + jp;
            if (n < NV) {
                f32x2 val = { acc[2 * jp] + biasv, acc[2 * jp + 1] + biasv };
                __builtin_nontemporal_store(val, (f32x2*)(out + (size_t)n * 128 + ocol));
            }
        }

        bar_lgkm();   // publish back buffer; front buffer reads all drained
        rbuf ^= 1;
    }
}

// ---- fallback (ws too small): fp32-gather kernel (unchanged) ----
__global__ __launch_bounds__(256, 4)
void onering_mfma_f32(const float* __restrict__ x,
                      const int* __restrict__ neigh,
                      const float* __restrict__ W,
                      const float* __restrict__ bias,
                      float* __restrict__ out,
                      int nchunks)
{
    __shared__ unsigned short A_lds[ROWS * ASTRIDE];
    const int tid  = threadIdx.x;
    const int lane = tid & 63;
    const int w    = tid >> 6;
    const int ncol = lane & 15;
    const int kgrp = lane >> 4;

    short8 bfrag[KSTEPS];
    {
        const int o = w * 16 + ncol;
#pragma unroll
        for (int s = 0; s < KSTEPS; ++s) {
            const int kb = s * 32 + kgrp * 8;
            const float4* wp = (const float4*)(W + o * KDIM + kb);
            float4 w0 = wp[0];
            float4 w1 = wp[1];
            union { short8 v; unsigned int u[4]; } pk;
            pk.u[0] = pack_bf16(w0.x, w0.y);
            pk.u[1] = pack_bf16(w0.z, w0.w);
            pk.u[2] = pack_bf16(w1.x, w1.y);
            pk.u[3] = pack_bf16(w1.z, w1.w);
            bfrag[s] = pk.v;
        }
    }
    const float biasv = bias[w * 16 + ncol];
    const int off4  = tid & 31;
    const int sbase = tid >> 5;

    for (int ch = blockIdx.x; ch < nchunks; ch += gridDim.x) {
        const int vb = ch * VPC;
        __syncthreads();
#pragma unroll
        for (int i = 0; i < 14; ++i) {
            const int s  = sbase + 8 * i;
            const int lv = s / 7;
            const int k  = s - lv * 7;
            const int n  = vb + lv;
            int vi = 0;
            if (n < NV) vi = neigh[n * KN + k];
            const float4 g = ((const float4*)x)[vi * 32 + off4];
            const int base = k * 64 + 2 * off4;
            ((unsigned int*)A_lds)[((lv * 2)     * ASTRIDE + base) >> 1] = pack_bf16(g.x, g.z);
            ((unsigned int*)A_lds)[((lv * 2 + 1) * ASTRIDE + base) >> 1] = pack_bf16(g.y, g.w);
        }
        __syncthreads();
        f32x4 acc0 = {0.f, 0.f, 0.f, 0.f};
        f32x4 acc1 = {0.f, 0.f, 0.f, 0.f};
#pragma unroll
        for (int s = 0; s < KSTEPS; ++s) {
            const int kb = s * 32 + kgrp * 8;
            const short8 a0 = *(const short8*)&A_lds[ncol * ASTRIDE + kb];
            const short8 a1 = *(const short8*)&A_lds[(16 + ncol) * ASTRIDE + kb];
            acc0 = __builtin_amdgcn_mfma_f32_16x16x32_bf16(a0, bfrag[s], acc0, 0, 0, 0);
            acc1 = __builtin_amdgcn_mfma_f32_16x16x32_bf16(a1, bfrag[s], acc1, 0, 0, 0);
        }
        const int o = w * 16 + ncol;
#pragma unroll
        for (int j = 0; j < 4; ++j) {
            const int r = kgrp * 4 + j;
            {
                const int lv = r >> 1, bb = r & 1, n = vb + lv;
                if (n < NV) out[n * 128 + o * 2 + bb] = acc0[j] + biasv;
            }
            {
                const int m = 16 + r;
                const int lv = m >> 1, bb = m & 1, n = vb + lv;
                if (n < NV) out[n * 128 + o * 2 + bb] = acc1[j] + biasv;
            }
        }
    }
}

extern "C" void kernel_launch(void* const* d_in, const int* in_sizes, int n_in,
                              void* d_out, int out_size, void* d_ws, size_t ws_size,
                              hipStream_t stream) {
    const float* x     = (const float*)d_in[0];
    const int*   neigh = (const int*)d_in[1];   // int64 in ref -> int32 from harness
    const float* W     = (const float*)d_in[2];
    const float* bias  = (const float*)d_in[3];
    float*       out   = (float*)d_out;

    const int nchunks = (NV + VPC - 1) / VPC;   // 10241
    const size_t need = (size_t)2 * NV * 64 * sizeof(unsigned short);  // 41.9 MB

    if (ws_size >= need) {
        unsigned short* xt = (unsigned short*)d_ws;
        const int nf4 = NV * 32;
        xcast<<<dim3((nf4 + 255) / 256), dim3(256), 0, stream>>>(x, (unsigned int*)xt, nf4);
        onering_mfma_bf16_v2<<<dim3(1024), dim3(512), 0, stream>>>(xt, neigh, W, bias, out, nchunks);
    } else {
        onering_mfma_f32<<<dim3(2560), dim3(256), 0, stream>>>(x, neigh, W, bias, out, nchunks);
    }
}